// Round 6
// baseline (219.963 us; speedup 1.0000x reference)
//
#include <hip/hip_runtime.h>

#define D256 256
#define TOTROWS 65536   // B*A*I = 4*32*512
#define BM 64           // rows per block = 2 x 32-row tiles
#define LDW 264         // padded LDS row stride in u16 (528 B): 0 bank conflicts
#define NBLK (TOTROWS / BM)   // 1024
#define NT 256                // 4 waves; wave wv owns panels {2wv, 2wv+1}, both tiles

typedef unsigned short u16;
typedef unsigned int u32;
typedef __attribute__((ext_vector_type(8))) short bf16x8;
typedef __attribute__((ext_vector_type(16))) float f32x16;

__device__ __forceinline__ float b2f(u16 u) {
  union { u32 i; float f; } v; v.i = ((u32)u) << 16; return v.f;
}
__device__ __forceinline__ u16 f2b(float f) {
  union { float f; u32 i; } v; v.f = f;
  return (u16)((v.i + 0x7fffu + ((v.i >> 16) & 1u)) >> 16);  // RNE
}
// packed RNE f32x2 -> bf16x2 (single VALU instr; bit-identical to f2b)
__device__ __forceinline__ u32 f2b2(float lo, float hi) {
  u32 r;
  asm("v_cvt_pk_bf16_f32 %0, %1, %2" : "=v"(r) : "v"(lo), "v"(hi));
  return r;
}

// Build weight fragments in MFMA B-operand lane order, bf16 (verified r0-r5):
//   Wf[m][p][k][ln] (16B chunk) = Brow[m][col = p*32 + (ln&31)][k*16 + (ln>>5)*8 ..+8]
// Brow[0]=attn1, Brow[1]=attn2 (row-major [n][k]); Brow[2][n][j]=W1[j][n]; Brow[3][n][j]=W2[j][n].
__global__ void build_wfrag(const float* __restrict__ a1,
                            const float* __restrict__ a2,
                            const float* __restrict__ W1,
                            const float* __restrict__ W2,
                            u16* __restrict__ Wf) {
  const int m = blockIdx.y;
  const int idx = blockIdx.x * 256 + threadIdx.x;   // 0..8191 per matrix
  int col, c;
  const float* src;
  if (m < 2) { col = idx >> 5; c = idx & 31; src = m ? a2 : a1; }
  else       { col = idx & 255; c = idx >> 8; src = (m == 3) ? W2 : W1; }
  const int kk0 = c * 8;
  const int p = col >> 5, l31 = col & 31, lhh = c & 1, k = c >> 1;
  const int ln = lhh * 32 + l31;
  u16* dst = Wf + m * 65536 + ((p * 16 + k) * 64 + ln) * 8;
  u16 v[8];
  if (m < 2) {
#pragma unroll
    for (int j = 0; j < 8; j++) v[j] = f2b(src[col * 256 + kk0 + j]);
  } else {
#pragma unroll
    for (int j = 0; j < 8; j++) v[j] = f2b(src[(kk0 + j) * 256 + col]);
  }
  ushort4 lo, hi;
  lo.x = v[0]; lo.y = v[1]; lo.z = v[2]; lo.w = v[3];
  hi.x = v[4]; hi.y = v[5]; hi.z = v[6]; hi.w = v[7];
  ((ushort4*)dst)[0] = lo;
  ((ushort4*)dst)[1] = hi;
}

// split-reduce: v[16] per-lane partials (rows (r&3)+8*(r>>2)+4*lh, summed over the
// 32 lane-columns) -> accumulated into sp[row] (row 0..31). 31 shfls. (verified)
__device__ __forceinline__ void reduce_accum(float v[16], float* sp,
                                             int l31, int lh) {
#pragma unroll
  for (int r = 0; r < 8; r++) {
    float a = v[r]     + __shfl_xor(v[r],     1, 32);
    float b = v[r + 8] + __shfl_xor(v[r + 8], 1, 32);
    v[r] = (l31 & 1) ? b : a;
  }
#pragma unroll
  for (int r = 0; r < 4; r++) {
    float a = v[r]     + __shfl_xor(v[r],     2, 32);
    float b = v[r + 4] + __shfl_xor(v[r + 4], 2, 32);
    v[r] = (l31 & 2) ? b : a;
  }
#pragma unroll
  for (int r = 0; r < 2; r++) {
    float a = v[r]     + __shfl_xor(v[r],     4, 32);
    float b = v[r + 2] + __shfl_xor(v[r + 2], 4, 32);
    v[r] = (l31 & 4) ? b : a;
  }
  {
    float a = v[0] + __shfl_xor(v[0], 8, 32);
    float b = v[1] + __shfl_xor(v[1], 8, 32);
    v[0] = (l31 & 8) ? b : a;
  }
  v[0] += __shfl_xor(v[0], 16, 32);
  if (l31 < 16) {
    const int i = ((l31 & 1) << 3) | ((l31 & 2) << 1) | ((l31 & 4) >> 1) |
                  ((l31 & 8) >> 3);
    const int row = (i & 3) + 8 * (i >> 2) + 4 * lh;
    atomicAdd(&sp[row], v[0]);
  }
}

__global__ __launch_bounds__(NT, 2)
void fused(const float* __restrict__ X0g, const float* __restrict__ X1g,
           const u16* __restrict__ Wf, float* __restrict__ outg) {
  __shared__ u16 lX0[BM][LDW];   // 33.8 KB
  __shared__ u16 lX1[BM][LDW];   // 33.8 KB -> ~68.6 KB total, 2 blocks/CU
  __shared__ float sp0[BM], sp1[BM], sc0[BM], sc1[BM];

  const int t = threadIdx.x;
  const int row0 = blockIdx.x * BM;

  if (t < BM) sp0[t] = 0.f;
  else if (t < 2 * BM) sp1[t - BM] = 0.f;

  // ---- stage: fp32 global -> bf16 LDS (4096 float4/tensor, 16 iters; verified) ----
  {
    const float4* g0 = (const float4*)(X0g + (size_t)row0 * D256);
    const float4* g1 = (const float4*)(X1g + (size_t)row0 * D256);
    uint2* s0 = (uint2*)&lX0[0][0];   // row stride = 66 uint2
    uint2* s1 = (uint2*)&lX1[0][0];
#pragma unroll 4
    for (int i = 0; i < 16; i++) {
      const int e = i * NT + t;         // 64 float4 per row
      const int row = e >> 6;
      const int col = e & 63;
      float4 a = g0[e];
      float4 b = g1[e];
      uint2 pa, pb;
      pa.x = f2b2(a.x, a.y); pa.y = f2b2(a.z, a.w);
      pb.x = f2b2(b.x, b.y); pb.y = f2b2(b.z, b.w);
      s0[row * 66 + col] = pa;
      s1[row * 66 + col] = pb;
    }
  }
  __syncthreads();   // LDS tiles + sp zero-init visible

  const int ln  = t & 63;
  const int wv  = t >> 6;      // wave 0..3
  const int l31 = ln & 31;
  const int lh  = ln >> 5;
  const int cb0 = (2 * wv) * 32;       // panel pair owned by this wave
  const int cb1 = (2 * wv + 1) * 32;

  // fragment-ordered weight streams: 1KB contiguous per (mat, panel, k)
  const u16* wb[4][2];
#pragma unroll
  for (int m = 0; m < 4; m++) {
#pragma unroll
    for (int pp = 0; pp < 2; pp++) {
      wb[m][pp] = Wf + m * 65536 + ((2 * wv + pp) * 16) * 512 + ln * 8;
    }
  }

  // ---- gate k-loop: G[panel][gate][tile]; each weight frag feeds 2 row-tiles ----
  {
    f32x16 G[2][2][2];
#pragma unroll
    for (int a = 0; a < 2; a++)
#pragma unroll
      for (int b = 0; b < 2; b++)
#pragma unroll
        for (int c = 0; c < 2; c++)
#pragma unroll
          for (int i = 0; i < 16; i++) G[a][b][c][i] = 0.f;

#pragma unroll 4
    for (int k = 0; k < 16; k++) {
      bf16x8 af0a = *(const bf16x8*)(&lX0[l31][k * 16 + lh * 8]);
      bf16x8 af0b = *(const bf16x8*)(&lX0[32 + l31][k * 16 + lh * 8]);
      bf16x8 af1a = *(const bf16x8*)(&lX1[l31][k * 16 + lh * 8]);
      bf16x8 af1b = *(const bf16x8*)(&lX1[32 + l31][k * 16 + lh * 8]);
#pragma unroll
      for (int pp = 0; pp < 2; pp++) {
        bf16x8 wa1 = *(const bf16x8*)(wb[0][pp] + k * 512);
        bf16x8 wa2 = *(const bf16x8*)(wb[1][pp] + k * 512);
        G[pp][0][0] = __builtin_amdgcn_mfma_f32_32x32x16_bf16(af0a, wa1, G[pp][0][0], 0, 0, 0);
        G[pp][0][1] = __builtin_amdgcn_mfma_f32_32x32x16_bf16(af0b, wa1, G[pp][0][1], 0, 0, 0);
        G[pp][1][0] = __builtin_amdgcn_mfma_f32_32x32x16_bf16(af1a, wa2, G[pp][1][0], 0, 0, 0);
        G[pp][1][1] = __builtin_amdgcn_mfma_f32_32x32x16_bf16(af1b, wa2, G[pp][1][1], 0, 0, 0);
      }
    }

    // elementwise gate products, in-lane 2-panel accumulation, then one butterfly
    // pair per tile (half the shuffles of the 8-wave layout)
#pragma unroll
    for (int tt = 0; tt < 2; tt++) {
      float v0[16], v1[16];
#pragma unroll
      for (int r = 0; r < 16; r++) {
        const int row = tt * 32 + (r & 3) + 8 * (r >> 2) + 4 * lh;
        v0[r] = G[0][0][tt][r] * b2f(lX1[row][cb0 + l31]) +
                G[1][0][tt][r] * b2f(lX1[row][cb1 + l31]);   // gate0: Z0 * X1
        v1[r] = G[0][1][tt][r] * b2f(lX0[row][cb0 + l31]) +
                G[1][1][tt][r] * b2f(lX0[row][cb1 + l31]);   // gate1: Z1 * X0
      }
      reduce_accum(v0, sp0 + tt * 32, l31, lh);
      reduce_accum(v1, sp1 + tt * 32, l31, lh);
    }
  }
  __syncthreads();   // sp complete

  // shared sigmoid phase (one transcendental per row, not per store)
  if (t < BM)          sc0[t] = 1.f + 1.f / (1.f + __expf(-sp0[t]));
  else if (t < 2 * BM) sc1[t - BM] = 1.f + 1.f / (1.f + __expf(-sp1[t - BM]));
  __syncthreads();   // sc visible

  // ---- proj k-loop: P[panel][mat][tile]; same frag reuse across tiles ----
  {
    f32x16 P[2][2][2];
#pragma unroll
    for (int a = 0; a < 2; a++)
#pragma unroll
      for (int b = 0; b < 2; b++)
#pragma unroll
        for (int c = 0; c < 2; c++)
#pragma unroll
          for (int i = 0; i < 16; i++) P[a][b][c][i] = 0.f;

#pragma unroll 4
    for (int k = 0; k < 16; k++) {
      bf16x8 af0a = *(const bf16x8*)(&lX0[l31][k * 16 + lh * 8]);
      bf16x8 af0b = *(const bf16x8*)(&lX0[32 + l31][k * 16 + lh * 8]);
      bf16x8 af1a = *(const bf16x8*)(&lX1[l31][k * 16 + lh * 8]);
      bf16x8 af1b = *(const bf16x8*)(&lX1[32 + l31][k * 16 + lh * 8]);
#pragma unroll
      for (int pp = 0; pp < 2; pp++) {
        bf16x8 ww1 = *(const bf16x8*)(wb[2][pp] + k * 512);
        bf16x8 ww2 = *(const bf16x8*)(wb[3][pp] + k * 512);
        P[pp][0][0] = __builtin_amdgcn_mfma_f32_32x32x16_bf16(af0a, ww1, P[pp][0][0], 0, 0, 0);
        P[pp][0][1] = __builtin_amdgcn_mfma_f32_32x32x16_bf16(af0b, ww1, P[pp][0][1], 0, 0, 0);
        P[pp][1][0] = __builtin_amdgcn_mfma_f32_32x32x16_bf16(af1a, ww2, P[pp][1][0], 0, 0, 0);
        P[pp][1][1] = __builtin_amdgcn_mfma_f32_32x32x16_bf16(af1b, ww2, P[pp][1][1], 0, 0, 0);
      }
    }

    // ---- epilogue: gate-scale and store (verified r0 pattern, per tile/panel) ----
#pragma unroll
    for (int tt = 0; tt < 2; tt++) {
#pragma unroll
      for (int pp = 0; pp < 2; pp++) {
        float* opb = outg + (size_t)(row0 + tt * 32) * D256 + (pp ? cb1 : cb0);
#pragma unroll
        for (int q = 0; q < 4; q++) {
          float s0a[4], s1a[4];
          *(float4*)s0a = *(const float4*)&sc0[tt * 32 + 8 * q + 4 * lh];
          *(float4*)s1a = *(const float4*)&sc1[tt * 32 + 8 * q + 4 * lh];
#pragma unroll
          for (int j = 0; j < 4; j++) {
            const int r = q * 4 + j;
            const int row = j + 8 * q + 4 * lh;
            __builtin_nontemporal_store(
                s0a[j] * P[pp][0][tt][r] + s1a[j] * P[pp][1][tt][r],
                &opb[row * D256 + l31]);
          }
        }
      }
    }
  }
}

extern "C" void kernel_launch(void* const* d_in, const int* in_sizes, int n_in,
                              void* d_out, int out_size, void* d_ws, size_t ws_size,
                              hipStream_t stream) {
  const float* i0 = (const float*)d_in[0];
  const float* i1 = (const float*)d_in[1];
  const float* W1 = (const float*)d_in[2];
  const float* W2 = (const float*)d_in[3];
  const float* a1 = (const float*)d_in[4];
  const float* a2 = (const float*)d_in[5];
  u16* Wf = (u16*)d_ws;   // 4 x 256x256 bf16 = 512 KB, fragment-ordered

  build_wfrag<<<dim3(32, 4), 256, 0, stream>>>(a1, a2, W1, W2, Wf);
  fused<<<NBLK, NT, 0, stream>>>(i0, i1, Wf, (float*)d_out);
}

// Round 7
// 203.737 us; speedup vs baseline: 1.0796x; 1.0796x over previous
//
#include <hip/hip_runtime.h>

#define D256 256
#define TOTROWS 65536   // B*A*I = 4*32*512
#define BM 64           // rows per block (2 x 32-row M-tiles per wave)
#define LDW 264         // padded LDS row stride in u16 (528 B): 0 bank conflicts
#define NBLK (TOTROWS / BM)   // 1024
#define NT 512                // 8 waves; wave wv owns 32-col panel wv

typedef unsigned short u16;
typedef unsigned int u32;
typedef __attribute__((ext_vector_type(8))) short bf16x8;
typedef __attribute__((ext_vector_type(16))) float f32x16;

__device__ __forceinline__ float b2f(u16 u) {
  union { u32 i; float f; } v; v.i = ((u32)u) << 16; return v.f;
}
__device__ __forceinline__ u16 f2b(float f) {
  union { float f; u32 i; } v; v.f = f;
  return (u16)((v.i + 0x7fffu + ((v.i >> 16) & 1u)) >> 16);  // RNE
}
// packed RNE f32x2 -> bf16x2 (single VALU instr; bit-identical to f2b)
__device__ __forceinline__ u32 f2b2(float lo, float hi) {
  u32 r;
  asm("v_cvt_pk_bf16_f32 %0, %1, %2" : "=v"(r) : "v"(lo), "v"(hi));
  return r;
}

// Build weight fragments in MFMA fragment lane order, bf16 (verified r0-r6):
//   Wf[m][p][k][ln] (16B chunk) = Brow[m][col = p*32 + (ln&31)][k*16 + (ln>>5)*8 ..+8]
// Brow[0]=attn1, Brow[1]=attn2 (row-major [n][k]); Brow[2][n][j]=W1[j][n]; Brow[3][n][j]=W2[j][n].
// Layout serves as B-operand (lane&31 = out col) AND as A-operand (lane&31 = out row)
// since A/B fragment layouts are mutually transposed.
__global__ void build_wfrag(const float* __restrict__ a1,
                            const float* __restrict__ a2,
                            const float* __restrict__ W1,
                            const float* __restrict__ W2,
                            u16* __restrict__ Wf) {
  const int m = blockIdx.y;
  const int idx = blockIdx.x * 256 + threadIdx.x;   // 0..8191 per matrix
  int col, c;
  const float* src;
  if (m < 2) { col = idx >> 5; c = idx & 31; src = m ? a2 : a1; }
  else       { col = idx & 255; c = idx >> 8; src = (m == 3) ? W2 : W1; }
  const int kk0 = c * 8;
  const int p = col >> 5, l31 = col & 31, lhh = c & 1, k = c >> 1;
  const int ln = lhh * 32 + l31;
  u16* dst = Wf + m * 65536 + ((p * 16 + k) * 64 + ln) * 8;
  u16 v[8];
  if (m < 2) {
#pragma unroll
    for (int j = 0; j < 8; j++) v[j] = f2b(src[col * 256 + kk0 + j]);
  } else {
#pragma unroll
    for (int j = 0; j < 8; j++) v[j] = f2b(src[(kk0 + j) * 256 + col]);
  }
  ushort4 lo, hi;
  lo.x = v[0]; lo.y = v[1]; lo.z = v[2]; lo.w = v[3];
  hi.x = v[4]; hi.y = v[5]; hi.z = v[6]; hi.w = v[7];
  ((ushort4*)dst)[0] = lo;
  ((ushort4*)dst)[1] = hi;
}

__global__ __launch_bounds__(NT, 4)
void fused(const float* __restrict__ X0g, const float* __restrict__ X1g,
           const u16* __restrict__ Wf, float* __restrict__ outg) {
  __shared__ u16 lX0[BM][LDW];   // 33.8 KB
  __shared__ u16 lX1[BM][LDW];   // 33.8 KB -> 68.6 KB total, 2 blocks/CU
  __shared__ float sp0[BM], sp1[BM], sc0[BM], sc1[BM];

  const int t = threadIdx.x;
  const int row0 = blockIdx.x * BM;

  if (t < BM) { sp0[t] = 0.f; }
  else if (t < 2 * BM) { sp1[t - BM] = 0.f; }

  // ---- stage: fp32 global -> bf16 LDS (4096 float4/tensor, 8 iters; verified) ----
  {
    const float4* g0 = (const float4*)(X0g + (size_t)row0 * D256);
    const float4* g1 = (const float4*)(X1g + (size_t)row0 * D256);
    uint2* s0 = (uint2*)&lX0[0][0];   // row stride = 66 uint2
    uint2* s1 = (uint2*)&lX1[0][0];
#pragma unroll 4
    for (int i = 0; i < 8; i++) {
      const int e = i * NT + t;         // 64 float4 per row
      const int row = e >> 6;
      const int col = e & 63;
      float4 a = g0[e];
      float4 b = g1[e];
      uint2 pa, pb;
      pa.x = f2b2(a.x, a.y); pa.y = f2b2(a.z, a.w);
      pb.x = f2b2(b.x, b.y); pb.y = f2b2(b.z, b.w);
      s0[row * 66 + col] = pa;
      s1[row * 66 + col] = pb;
    }
  }
  __syncthreads();   // LDS tiles + sp zero-init visible

  const int ln  = t & 63;
  const int wv  = t >> 6;      // wave 0..7 = column panel
  const int l31 = ln & 31;
  const int lh  = ln >> 5;
  const int cb  = wv * 32;

  // fragment-ordered weight streams: 1KB contiguous per (mat, k)
  const u16* wA1 = Wf + 0 * 65536 + (wv * 16) * 512 + ln * 8;
  const u16* wA2 = Wf + 1 * 65536 + (wv * 16) * 512 + ln * 8;
  const u16* wW1 = Wf + 2 * 65536 + (wv * 16) * 512 + ln * 8;
  const u16* wW2 = Wf + 3 * 65536 + (wv * 16) * 512 + ln * 8;

  // ---- pass 1: gate scores, SWAPPED operands: G = Z^T, data-row = lane&31 ----
  // Z0^T[j, row] = mfma(A = A1[j,k] frag, B = X0^T frag). Reduction axis j is
  // then in-lane (16 regs) -> no butterfly reduce needed.
  {
    f32x16 G0a, G0b, G1a, G1b;
#pragma unroll
    for (int i = 0; i < 16; i++) { G0a[i] = 0.f; G0b[i] = 0.f;
                                   G1a[i] = 0.f; G1b[i] = 0.f; }

#pragma unroll 2
    for (int k = 0; k < 16; k++) {
      bf16x8 w1 = *(const bf16x8*)(wA1 + k * 512);
      bf16x8 w2 = *(const bf16x8*)(wA2 + k * 512);
      bf16x8 a0a = *(const bf16x8*)(&lX0[l31][k * 16 + lh * 8]);
      bf16x8 a0b = *(const bf16x8*)(&lX0[32 + l31][k * 16 + lh * 8]);
      bf16x8 a1a = *(const bf16x8*)(&lX1[l31][k * 16 + lh * 8]);
      bf16x8 a1b = *(const bf16x8*)(&lX1[32 + l31][k * 16 + lh * 8]);
      G0a = __builtin_amdgcn_mfma_f32_32x32x16_bf16(w1, a0a, G0a, 0, 0, 0);
      G0b = __builtin_amdgcn_mfma_f32_32x32x16_bf16(w1, a0b, G0b, 0, 0, 0);
      G1a = __builtin_amdgcn_mfma_f32_32x32x16_bf16(w2, a1a, G1a, 0, 0, 0);
      G1b = __builtin_amdgcn_mfma_f32_32x32x16_bf16(w2, a1b, G1b, 0, 0, 0);
    }

    // gate finish: reg r holds j = (r&3) + 8*(r>>2) + 4*lh (4 groups of 4
    // consecutive j) for data row (tile*32 + l31). In-lane dot, one lh-swap
    // shuffle, one atomicAdd per (gate, tile).
#pragma unroll
    for (int tt = 0; tt < 2; tt++) {
      const u16* xr1 = &lX1[tt * 32 + l31][cb + 4 * lh];
      const u16* xr0 = &lX0[tt * 32 + l31][cb + 4 * lh];
      const f32x16& Gt0 = tt ? G0b : G0a;   // gate0: Z0 (X0@A1^T) * X1
      const f32x16& Gt1 = tt ? G1b : G1a;   // gate1: Z1 (X1@A2^T) * X0
      float v0 = 0.f, v1 = 0.f;
#pragma unroll
      for (int g = 0; g < 4; g++) {
        ushort4 a = *(const ushort4*)(xr1 + 8 * g);
        ushort4 b = *(const ushort4*)(xr0 + 8 * g);
        v0 += Gt0[g * 4 + 0] * b2f(a.x) + Gt0[g * 4 + 1] * b2f(a.y) +
              Gt0[g * 4 + 2] * b2f(a.z) + Gt0[g * 4 + 3] * b2f(a.w);
        v1 += Gt1[g * 4 + 0] * b2f(b.x) + Gt1[g * 4 + 1] * b2f(b.y) +
              Gt1[g * 4 + 2] * b2f(b.z) + Gt1[g * 4 + 3] * b2f(b.w);
      }
      v0 += __shfl_xor(v0, 32, 64);   // combine lh halves (j-split)
      v1 += __shfl_xor(v1, 32, 64);
      if (lh == 0) {
        atomicAdd(&sp0[tt * 32 + l31], v0);   // combine 8 panels
        atomicAdd(&sp1[tt * 32 + l31], v1);
      }
    }
  }
  __syncthreads();   // sp complete

  // sigmoid by first 128 threads; other waves proceed into pass 2.
  if (t < BM) {
    sc0[t] = 1.f + 1.f / (1.f + __expf(-sp0[t]));
  } else if (t < 2 * BM) {
    sc1[t - BM] = 1.f + 1.f / (1.f + __expf(-sp1[t - BM]));
  }

  // ---- pass 2: projections (unswapped: col = lane for coalesced stores) ----
  {
    f32x16 P0a, P0b, P1a, P1b;
#pragma unroll
    for (int i = 0; i < 16; i++) { P0a[i] = 0.f; P0b[i] = 0.f;
                                   P1a[i] = 0.f; P1b[i] = 0.f; }

#pragma unroll 2
    for (int k = 0; k < 16; k++) {
      bf16x8 w1 = *(const bf16x8*)(wW1 + k * 512);
      bf16x8 w2 = *(const bf16x8*)(wW2 + k * 512);
      bf16x8 a0a = *(const bf16x8*)(&lX0[l31][k * 16 + lh * 8]);
      bf16x8 a0b = *(const bf16x8*)(&lX0[32 + l31][k * 16 + lh * 8]);
      bf16x8 a1a = *(const bf16x8*)(&lX1[l31][k * 16 + lh * 8]);
      bf16x8 a1b = *(const bf16x8*)(&lX1[32 + l31][k * 16 + lh * 8]);
      P0a = __builtin_amdgcn_mfma_f32_32x32x16_bf16(a0a, w1, P0a, 0, 0, 0);
      P0b = __builtin_amdgcn_mfma_f32_32x32x16_bf16(a0b, w1, P0b, 0, 0, 0);
      P1a = __builtin_amdgcn_mfma_f32_32x32x16_bf16(a1a, w2, P1a, 0, 0, 0);
      P1b = __builtin_amdgcn_mfma_f32_32x32x16_bf16(a1b, w2, P1b, 0, 0, 0);
    }

    __syncthreads();   // sc0/sc1 ready + visible

    float* opb = outg + (size_t)row0 * 256 + cb;
#pragma unroll
    for (int q = 0; q < 4; q++) {
      float s0a[4], s1a[4], s0b[4], s1b[4];
      *(float4*)s0a = *(const float4*)&sc0[8 * q + 4 * lh];
      *(float4*)s1a = *(const float4*)&sc1[8 * q + 4 * lh];
      *(float4*)s0b = *(const float4*)&sc0[32 + 8 * q + 4 * lh];
      *(float4*)s1b = *(const float4*)&sc1[32 + 8 * q + 4 * lh];
#pragma unroll
      for (int j = 0; j < 4; j++) {
        const int r = q * 4 + j;
        const int row = j + 8 * q + 4 * lh;
        __builtin_nontemporal_store(s0a[j] * P0a[r] + s1a[j] * P1a[r],
                                    &opb[row * 256 + l31]);
        __builtin_nontemporal_store(s0b[j] * P0b[r] + s1b[j] * P1b[r],
                                    &opb[(32 + row) * 256 + l31]);
      }
    }
  }
}

extern "C" void kernel_launch(void* const* d_in, const int* in_sizes, int n_in,
                              void* d_out, int out_size, void* d_ws, size_t ws_size,
                              hipStream_t stream) {
  const float* i0 = (const float*)d_in[0];
  const float* i1 = (const float*)d_in[1];
  const float* W1 = (const float*)d_in[2];
  const float* W2 = (const float*)d_in[3];
  const float* a1 = (const float*)d_in[4];
  const float* a2 = (const float*)d_in[5];
  u16* Wf = (u16*)d_ws;   // 4 x 256x256 bf16 = 512 KB, fragment-ordered

  build_wfrag<<<dim3(32, 4), 256, 0, stream>>>(a1, a2, W1, W2, Wf);
  fused<<<NBLK, NT, 0, stream>>>(i0, i1, Wf, (float*)d_out);
}